// Round 8
// baseline (339.292 us; speedup 1.0000x reference)
//
#include <hip/hip_runtime.h>
#include <math.h>

#define BB 16
#define NN 25200
#define NCLS 80
#define TOPK 1000
#define MAXDET 100
#define TIE_CAP 4096
#define CAND_CAP 1024
#define BPI_C 99    // blocks/img for k_compact: ceil(25200/256)
#define BPI_S 394   // blocks/img for k_score:  ceil(25200*4/256)
static constexpr float NEGV = -1000000000.0f;
static constexpr float IMGSZ = 640.0f;

struct Meta {
  unsigned b1;
  unsigned c_gt;
  unsigned cnt;
  unsigned tie_cnt;
};

__device__ __forceinline__ unsigned flipKey(float f) {
  unsigned u = __float_as_uint(f);
  return (u & 0x80000000u) ? ~u : (u | 0x80000000u);
}
__device__ __forceinline__ float unflipKey(unsigned k) {
  unsigned u = (k & 0x80000000u) ? (k & 0x7FFFFFFFu) : ~k;
  return __uint_as_float(u);
}

// 32-bit unsigned max DPP step (bound_ctrl=1 -> invalid lanes read 0 = identity)
#define UMAX_DPP(VAR, CTRL)                                                                   \
  {                                                                                           \
    unsigned _o = (unsigned)__builtin_amdgcn_update_dpp(0, (int)(VAR), CTRL, 0xF, 0xF, true); \
    if (_o > (VAR)) (VAR) = _o;                                                               \
  }

// (hi,lo) 64-bit-ordered max DPP step
#define U64MAX_DPP(H, L, CTRL)                                                                 \
  {                                                                                            \
    unsigned _oh = (unsigned)__builtin_amdgcn_update_dpp(0, (int)(H), CTRL, 0xF, 0xF, true);   \
    unsigned _ol = (unsigned)__builtin_amdgcn_update_dpp(0, (int)(L), CTRL, 0xF, 0xF, true);   \
    bool _g = (_oh > (H)) || ((_oh == (H)) && (_ol > (L)));                                    \
    (H) = _g ? _oh : (H);                                                                      \
    (L) = _g ? _ol : (L);                                                                      \
  }

// ---------------- phase 1: scores + high-16 histogram (4 lanes per row) ----------------
__global__ void __launch_bounds__(256) k_score(const float* __restrict__ regs,
                                               const float* __restrict__ clses,
                                               unsigned* __restrict__ keys,
                                               float* __restrict__ ccs,
                                               int* __restrict__ preds,
                                               unsigned* __restrict__ hist1) {
  int img = blockIdx.x / BPI_S;
  int t = (blockIdx.x % BPI_S) * 256 + threadIdx.x;
  int rl = t >> 2, q = t & 3;
  if (rl >= NN) return;
  size_t row = (size_t)img * NN + (size_t)rl;
  const float4* r4 = reinterpret_cast<const float4*>(clses + row * NCLS);
  float best = -1.0f;
  int bi = 0;
#pragma unroll
  for (int u = 0; u < 5; ++u) {
    float4 v = r4[q + 4 * u];
    int b0 = (q + 4 * u) * 4;
    if (v.x > best) { best = v.x; bi = b0 + 0; }
    if (v.y > best) { best = v.y; bi = b0 + 1; }
    if (v.z > best) { best = v.z; bi = b0 + 2; }
    if (v.w > best) { best = v.w; bi = b0 + 3; }
  }
  unsigned vb = __float_as_uint(best);
  unsigned m = vb;
  UMAX_DPP(m, 0xB1);  // quad_perm [1,0,3,2]
  UMAX_DPP(m, 0x4E);  // quad_perm [2,3,0,1]
  unsigned t2 = (vb == m) ? (unsigned)(79 - bi) : 0u;
  UMAX_DPP(t2, 0xB1);
  UMAX_DPP(t2, 0x4E);
  if (q == 0) {
    float bestv = __uint_as_float(m);
    int bidx = 79 - (int)t2;
    float pobj = regs[row * 5 + 4];
    float sc = pobj * bestv;
    float s = (sc >= 0.05f) ? sc : NEGV;
    unsigned key = flipKey(s);
    keys[row] = key;
    ccs[row] = bestv;
    preds[row] = bidx;
    atomicAdd(&hist1[(size_t)img * 65536 + (key >> 16)], 1u);
  }
}

// ---------------- histogram scan (single level): find cutoff high-16 bin ----------------
__global__ void __launch_bounds__(256) k_scan(const unsigned* __restrict__ hist,
                                              Meta* __restrict__ meta) {
  __shared__ unsigned part[256];
  __shared__ unsigned sfx[256];
  __shared__ int s_sel;
  __shared__ unsigned s_cum;
  int img = blockIdx.x;
  int t = threadIdx.x;
  const unsigned* h = hist + (size_t)img * 65536;
  const unsigned target = (unsigned)TOPK;
  unsigned s = 0;
  const uint4* h4 = reinterpret_cast<const uint4*>(h) + (size_t)t * 64;
  for (int j = 0; j < 64; ++j) {
    uint4 v = h4[j];
    s += v.x + v.y + v.z + v.w;
  }
  part[t] = s;
  sfx[t] = s;
  __syncthreads();
  for (int d = 1; d < 256; d <<= 1) {
    unsigned v = (t + d < 256) ? sfx[t + d] : 0u;
    __syncthreads();
    sfx[t] += v;
    __syncthreads();
  }
  {
    unsigned incl = sfx[t];
    unsigned excl = incl - part[t];
    if (incl >= target && excl < target) { s_sel = t; s_cum = excl; }
  }
  __syncthreads();
  int chunk = s_sel;
  unsigned cumAbove = s_cum;
  __syncthreads();
  unsigned b = h[(size_t)chunk * 256 + t];
  part[t] = b;
  sfx[t] = b;
  __syncthreads();
  for (int d = 1; d < 256; d <<= 1) {
    unsigned v = (t + d < 256) ? sfx[t + d] : 0u;
    __syncthreads();
    sfx[t] += v;
    __syncthreads();
  }
  {
    unsigned incl = cumAbove + sfx[t];
    unsigned excl = incl - part[t];
    if (incl >= target && excl < target) {
      meta[img].b1 = (unsigned)(chunk * 256 + t);
      meta[img].c_gt = excl;
    }
  }
}

// ---------------- decode + candidate write (global) ----------------
__device__ __forceinline__ void decode_write(int img, unsigned pos, int i,
                                             const float* __restrict__ regs,
                                             const float* __restrict__ anchors,
                                             float score, float cc, int pred,
                                             float* __restrict__ cand) {
  const size_t S = (size_t)BB * CAND_CAP;
  size_t g = (size_t)img * NN + (size_t)i;
  const float* r = regs + g * 5;
  float d0 = r[0], d1 = r[1], d2 = r[2], d3 = r[3], obj = r[4];
  const float* a = anchors + (size_t)i * 4;
  float ax1 = a[0], ay1 = a[1], ax2 = a[2], ay2 = a[3];
  float aw = ax2 - ax1, ah = ay2 - ay1;
  float acx = (ax1 + ax2) * 0.5f, acy = (ay1 + ay2) * 0.5f;
  float cx = acx + d0 * aw, cy = acy + d1 * ah;
  float w = aw * expf(d2), h = ah * expf(d3);
  float hw = 0.5f * w, hh = 0.5f * h;
  float x1 = fminf(fmaxf(cx - hw, 0.0f), IMGSZ);
  float y1 = fminf(fmaxf(cy - hh, 0.0f), IMGSZ);
  float x2 = fminf(fmaxf(cx + hw, 0.0f), IMGSZ);
  float y2 = fminf(fmaxf(cy + hh, 0.0f), IMGSZ);
  size_t o = (size_t)img * CAND_CAP + pos;
  cand[0 * S + o] = x1;
  cand[1 * S + o] = y1;
  cand[2 * S + o] = x2;
  cand[3 * S + o] = y2;
  cand[4 * S + o] = obj;
  cand[5 * S + o] = cc;
  cand[6 * S + o] = (float)pred;
  cand[7 * S + o] = score;
  reinterpret_cast<unsigned*>(cand + 8 * S)[o] = (unsigned)i;
}

// ---------------- compaction: wave-aggregated atomics (1 atomic/wave) ----------------
__global__ void k_compact(const float* __restrict__ regs, const float* __restrict__ anchors,
                          const unsigned* __restrict__ keys, const float* __restrict__ ccs,
                          const int* __restrict__ preds, Meta* __restrict__ meta,
                          float* __restrict__ cand, unsigned long long* __restrict__ ties) {
  int img = blockIdx.x / BPI_C;
  int i = (blockIdx.x % BPI_C) * 256 + threadIdx.x;
  if (i >= NN) return;
  int lane = threadIdx.x & 63;
  unsigned long long lt = (1ull << lane) - 1ull;
  size_t g = (size_t)img * NN + (size_t)i;
  unsigned key = keys[g];
  unsigned k16 = key >> 16;
  unsigned b1 = meta[img].b1;

  bool above = k16 > b1;
  unsigned long long mA = __ballot(above);
  if (above) {
    int leader = __builtin_ctzll(mA);
    unsigned base = 0;
    if (lane == leader) base = atomicAdd(&meta[img].cnt, (unsigned)__popcll(mA));
    base = __shfl(base, leader);
    unsigned pos = base + (unsigned)__popcll(mA & lt);
    if (pos < CAND_CAP)
      decode_write(img, pos, i, regs, anchors, unflipKey(key), ccs[g], preds[g], cand);
  }
  bool tie = (k16 == b1);
  unsigned long long mT = __ballot(tie);
  if (tie) {
    int leader = __builtin_ctzll(mT);
    unsigned base = 0;
    if (lane == leader) base = atomicAdd(&meta[img].tie_cnt, (unsigned)__popcll(mT));
    base = __shfl(base, leader);
    unsigned tp = base + (unsigned)__popcll(mT & lt);
    if (tp < TIE_CAP)
      ties[(size_t)img * TIE_CAP + tp] =
          ((unsigned long long)key << 15) | (unsigned long long)(0x7FFFu - (unsigned)i);
  }
}

// ---------------- NMS: ONE wave per image, boxes in REGISTERS (512-VGPR budget) --------
// __launch_bounds__(64,1) lifts the VGPR cap (R5's spill was the 132-cap, not the design).
// Live state: 5 box floats + 2 key words x16 cand = 112 VGPR. Per iter, serial chain:
// 64-bit local-max tree -> 6-step 64-bit DPP reduce -> readlane x2 -> ONE uniform
// ds_read_b128 (winner box) -> 16 in-register division-free IoU -> ds_write wins[it].
// No barriers, no polls, no payload gathering in the loop (epilogue gathers via wins[]).
__global__ void __launch_bounds__(64, 1) k_nms(const float* __restrict__ cand,
                                               const Meta* __restrict__ meta,
                                               float* __restrict__ out,
                                               const float* __restrict__ regs,
                                               const float* __restrict__ anchors,
                                               const float* __restrict__ ccs,
                                               const int* __restrict__ preds,
                                               const unsigned long long* __restrict__ ties) {
  const size_t S = (size_t)BB * CAND_CAP;
  int img = blockIdx.x;
  int lane = threadIdx.x;

  __shared__ float4 boxo[CAND_CAP];         // offset boxes               16 KB
  __shared__ float4 pay0[CAND_CAP];         // x1,y1,x2,y2                16 KB
  __shared__ float4 pay1[CAND_CAP];         // obj,cc,cp,score            16 KB
  __shared__ unsigned idxA[CAND_CAP];       // anchor idx                  4 KB
  __shared__ unsigned wins[MAXDET];         // winner slots               400 B
  __shared__ float4 lout4[MAXDET * 7 / 4];  // output staging            2.8 KB
  float* lout = reinterpret_cast<float*>(lout4);

  unsigned cnt = meta[img].cnt;
  unsigned c_gt = meta[img].c_gt;
  unsigned tcnt = meta[img].tie_cnt;
  if (tcnt > TIE_CAP) tcnt = TIE_CAP;
  unsigned need = (unsigned)TOPK - c_gt;
  if (need > tcnt) need = tcnt;
  int n = (int)(cnt + need);

  float x1o[16], y1o[16], x2o[16], y2o[16], area[16];
  unsigned kh[16], kl[16];

  // ---- (1) main load: 16 slots/lane, boxes to registers AND LDS ----
#pragma unroll
  for (int k = 0; k < 16; ++k) {
    int c = k * 64 + lane;
    size_t o = (size_t)img * CAND_CAP + (size_t)c;
    bool v = c < (int)cnt;
    float vx1 = cand[0 * S + o], vy1 = cand[1 * S + o];
    float vx2 = cand[2 * S + o], vy2 = cand[3 * S + o];
    float vobj = cand[4 * S + o], vcc = cand[5 * S + o];
    float vcp = cand[6 * S + o], vsc = cand[7 * S + o];
    unsigned vai = reinterpret_cast<const unsigned*>(cand + 8 * S)[o];
    if (!v) { vx1 = vy1 = vx2 = vy2 = 0.f; vobj = vcc = vcp = 0.f; vsc = NEGV; vai = 0x7FFFu; }
    float offv = vcp * 4096.0f;
    float a1 = vx1 + offv, b1 = vy1 + offv, a2 = vx2 + offv, b2 = vy2 + offv;
    x1o[k] = a1; y1o[k] = b1; x2o[k] = a2; y2o[k] = b2;
    area[k] = (a2 - a1) * (b2 - b1);
    boxo[c] = make_float4(a1, b1, a2, b2);
    pay0[c] = make_float4(vx1, vy1, vx2, vy2);
    pay1[c] = make_float4(vobj, vcc, vcp, vsc);
    idxA[c] = vai;
    kh[k] = flipKey(vsc);
    kl[k] = (((0x7FFFu - vai) & 0x7FFFu) << 10) | (unsigned)c;
  }
  // wins sentinel init
  if (lane < 50) { wins[lane] = 0xFFFFFFFFu; wins[lane + 50] = 0xFFFFFFFFu; }

  // ---- (2) tie rank-select: rank = #ties with bigger 62-bit key; parallel decode ----
  {
    const unsigned long long* tptr = ties + (size_t)img * TIE_CAP;
    for (unsigned base = 0; base < tcnt; base += 64) {
      unsigned p = base + (unsigned)lane;
      unsigned long long myk = (p < tcnt) ? tptr[p] : 0ull;
      unsigned rank = 0;
      for (unsigned q2 = 0; q2 < tcnt; ++q2) {
        unsigned long long other = tptr[q2];  // wave-uniform -> broadcast
        rank += (other > myk) ? 1u : 0u;
      }
      if (p < tcnt && rank < need) {
        unsigned idx = 0x7FFFu - (unsigned)(myk & 0x7FFFull);
        unsigned key32 = (unsigned)(myk >> 15);
        size_t g = (size_t)img * NN + idx;
        const float* r = regs + g * 5;
        float d0 = r[0], d1 = r[1], d2 = r[2], d3 = r[3], obj = r[4];
        const float* a = anchors + (size_t)idx * 4;
        float ax1 = a[0], ay1 = a[1], ax2 = a[2], ay2 = a[3];
        float aw = ax2 - ax1, ah = ay2 - ay1;
        float acx = (ax1 + ax2) * 0.5f, acy = (ay1 + ay2) * 0.5f;
        float cx = acx + d0 * aw, cy = acy + d1 * ah;
        float w = aw * expf(d2), h = ah * expf(d3);
        float hw = 0.5f * w, hh = 0.5f * h;
        float x1 = fminf(fmaxf(cx - hw, 0.0f), IMGSZ);
        float y1 = fminf(fmaxf(cy - hh, 0.0f), IMGSZ);
        float x2 = fminf(fmaxf(cx + hw, 0.0f), IMGSZ);
        float y2 = fminf(fmaxf(cy + hh, 0.0f), IMGSZ);
        float cc = ccs[g];
        float cp = (float)preds[g];
        float offv = cp * 4096.0f;
        int c = (int)(cnt + rank);
        boxo[c] = make_float4(x1 + offv, y1 + offv, x2 + offv, y2 + offv);
        pay0[c] = make_float4(x1, y1, x2, y2);
        pay1[c] = make_float4(obj, cc, cp, unflipKey(key32));
        idxA[c] = idx;
      }
    }
  }
  __syncthreads();  // single wave: cheap; publishes scattered tie writes

  // ---- (3) tie reg-init: owning lanes pull tie slots from LDS ----
#pragma unroll
  for (int k = 0; k < 16; ++k) {
    int c = k * 64 + lane;
    if (c >= (int)cnt && c < n) {
      float4 B = boxo[c];
      float4 p1 = pay1[c];
      unsigned vai = idxA[c];
      x1o[k] = B.x; y1o[k] = B.y; x2o[k] = B.z; y2o[k] = B.w;
      area[k] = (B.z - B.x) * (B.w - B.y);
      kh[k] = flipKey(p1.w);
      kl[k] = (((0x7FFFu - vai) & 0x7FFFu) << 10) | (unsigned)c;
    }
  }

  const unsigned validThr = flipKey(NEGV * 0.5f);

  // ---- (4) iteration loop: zero sync, one LDS read on the chain ----
  for (int it = 0; it < MAXDET; ++it) {
    // balanced 64-bit local max tree over 16 candidates
    unsigned th[8], tl[8];
#pragma unroll
    for (int k = 0; k < 8; ++k) {
      bool g = (kh[2 * k + 1] > kh[2 * k]) ||
               ((kh[2 * k + 1] == kh[2 * k]) && (kl[2 * k + 1] > kl[2 * k]));
      th[k] = g ? kh[2 * k + 1] : kh[2 * k];
      tl[k] = g ? kl[2 * k + 1] : kl[2 * k];
    }
#pragma unroll
    for (int k = 0; k < 4; ++k) {
      bool g = (th[2 * k + 1] > th[2 * k]) ||
               ((th[2 * k + 1] == th[2 * k]) && (tl[2 * k + 1] > tl[2 * k]));
      th[k] = g ? th[2 * k + 1] : th[2 * k];
      tl[k] = g ? tl[2 * k + 1] : tl[2 * k];
    }
    {
      bool g = (th[1] > th[0]) || ((th[1] == th[0]) && (tl[1] > tl[0]));
      th[0] = g ? th[1] : th[0];
      tl[0] = g ? tl[1] : tl[0];
      g = (th[3] > th[2]) || ((th[3] == th[2]) && (tl[3] > tl[2]));
      th[2] = g ? th[3] : th[2];
      tl[2] = g ? tl[3] : tl[2];
      g = (th[2] > th[0]) || ((th[2] == th[0]) && (tl[2] > tl[0]));
      th[0] = g ? th[2] : th[0];
      tl[0] = g ? tl[2] : tl[0];
    }
    unsigned mh = th[0], ml = tl[0];
    U64MAX_DPP(mh, ml, 0x111);
    U64MAX_DPP(mh, ml, 0x112);
    U64MAX_DPP(mh, ml, 0x114);
    U64MAX_DPP(mh, ml, 0x118);
    U64MAX_DPP(mh, ml, 0x142);
    U64MAX_DPP(mh, ml, 0x143);
    unsigned bh = (unsigned)__builtin_amdgcn_readlane((int)mh, 63);
    unsigned bl = (unsigned)__builtin_amdgcn_readlane((int)ml, 63);

    if (bh <= validThr) break;  // wins[] stays sentinel -> epilogue zero-fills

    int slot = (int)(bl & 1023u);
    if (lane == 0) wins[it] = (unsigned)slot;  // fire-and-forget
    float4 B = boxo[slot];                     // ONE uniform ds_read_b128
    float areaB = (B.z - B.x) * (B.w - B.y);
#pragma unroll
    for (int k = 0; k < 16; ++k) {
      int c = k * 64 + lane;
      float lx = fmaxf(B.x, x1o[k]), ly = fmaxf(B.y, y1o[k]);
      float rx = fminf(B.z, x2o[k]), ry = fminf(B.w, y2o[k]);
      float iw = fmaxf(rx - lx, 0.f), ih = fmaxf(ry - ly, 0.f);
      float inter = iw * ih;
      float uu = areaB + area[k] - inter;
      float ss = fmaf(2.0f, inter, -uu);  // exact 2i-u in the decision region (Sterbenz)
      float tt = uu * 0x1p-24f;           // exact scale; RN(i/u)>0.5 <=> ss>tt
      bool sup = (ss > tt) || (c == slot);  // u<=0 => ss=0,tt=0 -> not suppressed (matches ref)
      if (sup) { kh[k] = 0u; kl[k] = 0u; }
    }
  }
  __syncthreads();

  // ---- epilogue: gather winner payloads via wins[], stage rows, flush ----
  for (int r = lane; r < MAXDET; r += 64) {
    unsigned w = wins[r];
    float* row = lout + r * 7;
    if (w == 0xFFFFFFFFu) {
      row[0] = 0.f; row[1] = 0.f; row[2] = 0.f; row[3] = 0.f;
      row[4] = 0.f; row[5] = 0.f; row[6] = 0.f;
    } else {
      float4 p0 = pay0[w];
      float4 p1 = pay1[w];
      row[0] = p0.x; row[1] = p0.y; row[2] = p0.z; row[3] = p0.w;
      row[4] = p1.x; row[5] = p1.y; row[6] = p1.z;
    }
  }
  __syncthreads();
  float4* go4 = reinterpret_cast<float4*>(out + (size_t)img * MAXDET * 7);
  for (int p = lane; p < MAXDET * 7 / 4; p += 64) go4[p] = lout4[p];
}

// ---------------- launch ----------------
extern "C" void kernel_launch(void* const* d_in, const int* in_sizes, int n_in,
                              void* d_out, int out_size, void* d_ws, size_t ws_size,
                              hipStream_t stream) {
  const float* regs = (const float*)d_in[0];
  const float* clses = (const float*)d_in[1];
  const float* anchors = (const float*)d_in[2];
  float* out = (float*)d_out;
  char* ws = (char*)d_ws;

  constexpr size_t HIST_BYTES = (size_t)BB * 65536 * 4;  // 4 MiB
  constexpr size_t META_OFF = HIST_BYTES;
  constexpr size_t META_BYTES = 1024;
  constexpr size_t KEYS_OFF = META_OFF + META_BYTES;
  constexpr size_t ARR_BYTES = (size_t)BB * NN * 4;
  constexpr size_t CCS_OFF = KEYS_OFF + ARR_BYTES;
  constexpr size_t PREDS_OFF = CCS_OFF + ARR_BYTES;
  constexpr size_t CAND_OFF = PREDS_OFF + ARR_BYTES;
  constexpr size_t CAND_BYTES = (size_t)10 * BB * CAND_CAP * 4;
  constexpr size_t TIES_OFF = CAND_OFF + CAND_BYTES;

  unsigned* hist1 = (unsigned*)(ws);
  Meta* meta = (Meta*)(ws + META_OFF);
  unsigned* keys = (unsigned*)(ws + KEYS_OFF);
  float* ccs = (float*)(ws + CCS_OFF);
  int* preds = (int*)(ws + PREDS_OFF);
  float* cand = (float*)(ws + CAND_OFF);
  unsigned long long* ties = (unsigned long long*)(ws + TIES_OFF);

  // zero hist1 + meta every launch (ws is not re-poisoned between replays)
  hipMemsetAsync(d_ws, 0, KEYS_OFF, stream);

  k_score<<<BB * BPI_S, 256, 0, stream>>>(regs, clses, keys, ccs, preds, hist1);
  k_scan<<<BB, 256, 0, stream>>>(hist1, meta);
  k_compact<<<BB * BPI_C, 256, 0, stream>>>(regs, anchors, keys, ccs, preds, meta, cand, ties);
  k_nms<<<BB, 64, 0, stream>>>(cand, meta, out, regs, anchors, ccs, preds, ties);
}

// Round 9
// 205.609 us; speedup vs baseline: 1.6502x; 1.6502x over previous
//
#include <hip/hip_runtime.h>
#include <math.h>

#define BB 16
#define NN 25200
#define NCLS 80
#define TOPK 1000
#define MAXDET 100
#define TIE_CAP 4096
#define CAND_CAP 1024
#define BPI_C 99    // blocks/img for k_compact: ceil(25200/256)
#define BPI_S 394   // blocks/img for k_score:  ceil(25200*4/256)
static constexpr float NEGV = -1000000000.0f;
static constexpr float IMGSZ = 640.0f;

struct Meta {
  unsigned b1;
  unsigned c_gt;
  unsigned cnt;
  unsigned tie_cnt;
};

__device__ __forceinline__ unsigned flipKey(float f) {
  unsigned u = __float_as_uint(f);
  return (u & 0x80000000u) ? ~u : (u | 0x80000000u);
}
__device__ __forceinline__ float unflipKey(unsigned k) {
  unsigned u = (k & 0x80000000u) ? (k & 0x7FFFFFFFu) : ~k;
  return __uint_as_float(u);
}

// 32-bit unsigned max DPP step (bound_ctrl=1 -> invalid lanes read 0 = identity)
#define UMAX_DPP(VAR, CTRL)                                                                   \
  {                                                                                           \
    unsigned _o = (unsigned)__builtin_amdgcn_update_dpp(0, (int)(VAR), CTRL, 0xF, 0xF, true); \
    if (_o > (VAR)) (VAR) = _o;                                                               \
  }

// (hi,lo) 64-bit-ordered max DPP step
#define U64MAX_DPP(H, L, CTRL)                                                                 \
  {                                                                                            \
    unsigned _oh = (unsigned)__builtin_amdgcn_update_dpp(0, (int)(H), CTRL, 0xF, 0xF, true);   \
    unsigned _ol = (unsigned)__builtin_amdgcn_update_dpp(0, (int)(L), CTRL, 0xF, 0xF, true);   \
    bool _g = (_oh > (H)) || ((_oh == (H)) && (_ol > (L)));                                    \
    (H) = _g ? _oh : (H);                                                                      \
    (L) = _g ? _ol : (L);                                                                      \
  }

// ---------------- phase 1: scores + high-16 histogram (4 lanes per row) ----------------
__global__ void __launch_bounds__(256) k_score(const float* __restrict__ regs,
                                               const float* __restrict__ clses,
                                               unsigned* __restrict__ keys,
                                               float* __restrict__ ccs,
                                               int* __restrict__ preds,
                                               unsigned* __restrict__ hist1) {
  int img = blockIdx.x / BPI_S;
  int t = (blockIdx.x % BPI_S) * 256 + threadIdx.x;
  int rl = t >> 2, q = t & 3;
  if (rl >= NN) return;
  size_t row = (size_t)img * NN + (size_t)rl;
  const float4* r4 = reinterpret_cast<const float4*>(clses + row * NCLS);
  float best = -1.0f;
  int bi = 0;
#pragma unroll
  for (int u = 0; u < 5; ++u) {
    float4 v = r4[q + 4 * u];
    int b0 = (q + 4 * u) * 4;
    if (v.x > best) { best = v.x; bi = b0 + 0; }
    if (v.y > best) { best = v.y; bi = b0 + 1; }
    if (v.z > best) { best = v.z; bi = b0 + 2; }
    if (v.w > best) { best = v.w; bi = b0 + 3; }
  }
  unsigned vb = __float_as_uint(best);
  unsigned m = vb;
  UMAX_DPP(m, 0xB1);  // quad_perm [1,0,3,2]
  UMAX_DPP(m, 0x4E);  // quad_perm [2,3,0,1]
  unsigned t2 = (vb == m) ? (unsigned)(79 - bi) : 0u;
  UMAX_DPP(t2, 0xB1);
  UMAX_DPP(t2, 0x4E);
  if (q == 0) {
    float bestv = __uint_as_float(m);
    int bidx = 79 - (int)t2;
    float pobj = regs[row * 5 + 4];
    float sc = pobj * bestv;
    float s = (sc >= 0.05f) ? sc : NEGV;
    unsigned key = flipKey(s);
    keys[row] = key;
    ccs[row] = bestv;
    preds[row] = bidx;
    atomicAdd(&hist1[(size_t)img * 65536 + (key >> 16)], 1u);
  }
}

// ---------------- histogram scan (single level): find cutoff high-16 bin ----------------
__global__ void __launch_bounds__(256) k_scan(const unsigned* __restrict__ hist,
                                              Meta* __restrict__ meta) {
  __shared__ unsigned part[256];
  __shared__ unsigned sfx[256];
  __shared__ int s_sel;
  __shared__ unsigned s_cum;
  int img = blockIdx.x;
  int t = threadIdx.x;
  const unsigned* h = hist + (size_t)img * 65536;
  const unsigned target = (unsigned)TOPK;
  unsigned s = 0;
  const uint4* h4 = reinterpret_cast<const uint4*>(h) + (size_t)t * 64;
  for (int j = 0; j < 64; ++j) {
    uint4 v = h4[j];
    s += v.x + v.y + v.z + v.w;
  }
  part[t] = s;
  sfx[t] = s;
  __syncthreads();
  for (int d = 1; d < 256; d <<= 1) {
    unsigned v = (t + d < 256) ? sfx[t + d] : 0u;
    __syncthreads();
    sfx[t] += v;
    __syncthreads();
  }
  {
    unsigned incl = sfx[t];
    unsigned excl = incl - part[t];
    if (incl >= target && excl < target) { s_sel = t; s_cum = excl; }
  }
  __syncthreads();
  int chunk = s_sel;
  unsigned cumAbove = s_cum;
  __syncthreads();
  unsigned b = h[(size_t)chunk * 256 + t];
  part[t] = b;
  sfx[t] = b;
  __syncthreads();
  for (int d = 1; d < 256; d <<= 1) {
    unsigned v = (t + d < 256) ? sfx[t + d] : 0u;
    __syncthreads();
    sfx[t] += v;
    __syncthreads();
  }
  {
    unsigned incl = cumAbove + sfx[t];
    unsigned excl = incl - part[t];
    if (incl >= target && excl < target) {
      meta[img].b1 = (unsigned)(chunk * 256 + t);
      meta[img].c_gt = excl;
    }
  }
}

// ---------------- decode + candidate write (global) ----------------
__device__ __forceinline__ void decode_write(int img, unsigned pos, int i,
                                             const float* __restrict__ regs,
                                             const float* __restrict__ anchors,
                                             float score, float cc, int pred,
                                             float* __restrict__ cand) {
  const size_t S = (size_t)BB * CAND_CAP;
  size_t g = (size_t)img * NN + (size_t)i;
  const float* r = regs + g * 5;
  float d0 = r[0], d1 = r[1], d2 = r[2], d3 = r[3], obj = r[4];
  const float* a = anchors + (size_t)i * 4;
  float ax1 = a[0], ay1 = a[1], ax2 = a[2], ay2 = a[3];
  float aw = ax2 - ax1, ah = ay2 - ay1;
  float acx = (ax1 + ax2) * 0.5f, acy = (ay1 + ay2) * 0.5f;
  float cx = acx + d0 * aw, cy = acy + d1 * ah;
  float w = aw * expf(d2), h = ah * expf(d3);
  float hw = 0.5f * w, hh = 0.5f * h;
  float x1 = fminf(fmaxf(cx - hw, 0.0f), IMGSZ);
  float y1 = fminf(fmaxf(cy - hh, 0.0f), IMGSZ);
  float x2 = fminf(fmaxf(cx + hw, 0.0f), IMGSZ);
  float y2 = fminf(fmaxf(cy + hh, 0.0f), IMGSZ);
  size_t o = (size_t)img * CAND_CAP + pos;
  cand[0 * S + o] = x1;
  cand[1 * S + o] = y1;
  cand[2 * S + o] = x2;
  cand[3 * S + o] = y2;
  cand[4 * S + o] = obj;
  cand[5 * S + o] = cc;
  cand[6 * S + o] = (float)pred;
  cand[7 * S + o] = score;
  reinterpret_cast<unsigned*>(cand + 8 * S)[o] = (unsigned)i;
}

// ---------------- compaction: wave-aggregated atomics (1 atomic/wave) ----------------
__global__ void k_compact(const float* __restrict__ regs, const float* __restrict__ anchors,
                          const unsigned* __restrict__ keys, const float* __restrict__ ccs,
                          const int* __restrict__ preds, Meta* __restrict__ meta,
                          float* __restrict__ cand, unsigned long long* __restrict__ ties) {
  int img = blockIdx.x / BPI_C;
  int i = (blockIdx.x % BPI_C) * 256 + threadIdx.x;
  if (i >= NN) return;
  int lane = threadIdx.x & 63;
  unsigned long long lt = (1ull << lane) - 1ull;
  size_t g = (size_t)img * NN + (size_t)i;
  unsigned key = keys[g];
  unsigned k16 = key >> 16;
  unsigned b1 = meta[img].b1;

  bool above = k16 > b1;
  unsigned long long mA = __ballot(above);
  if (above) {
    int leader = __builtin_ctzll(mA);
    unsigned base = 0;
    if (lane == leader) base = atomicAdd(&meta[img].cnt, (unsigned)__popcll(mA));
    base = __shfl(base, leader);
    unsigned pos = base + (unsigned)__popcll(mA & lt);
    if (pos < CAND_CAP)
      decode_write(img, pos, i, regs, anchors, unflipKey(key), ccs[g], preds[g], cand);
  }
  bool tie = (k16 == b1);
  unsigned long long mT = __ballot(tie);
  if (tie) {
    int leader = __builtin_ctzll(mT);
    unsigned base = 0;
    if (lane == leader) base = atomicAdd(&meta[img].tie_cnt, (unsigned)__popcll(mT));
    base = __shfl(base, leader);
    unsigned tp = base + (unsigned)__popcll(mT & lt);
    if (tp < TIE_CAP)
      ties[(size_t)img * TIE_CAP + tp] =
          ((unsigned long long)key << 15) | (unsigned long long)(0x7FFFu - (unsigned)i);
  }
}

// ---------------- NMS: 4 waves/image, spin-sync with PARALLEL poll ----------------
// Mailbox u64 = tag7 | kh32 | sec25 (sec25 = (0x7FFF-ai)<<10 | slot10): with equal tags,
// plain u64 compare == full (score desc, idx asc, slot) order. Per iter: local 64-bit max
// (3 cmps) -> 6-step DPP wave max -> lane63 ds_write slot -> parallel poll (lane j reads
// slot j&3, ONE ballot tests all 4 tags) -> 2 quad-DPP max steps (every lane gets global
// best, no broadcast) -> uniform boxo[slot] read -> 4 in-register division-free IoUs.
// Winner payload gathering deferred to epilogue via wins[] (off the critical chain).
// Parity-double-buffered mailbox: write of parity p at iter it+2 is gated by every wave
// having consumed parity p at iter it (same protocol as validated R7).
__global__ void __launch_bounds__(256) k_nms(const float* __restrict__ cand,
                                             const Meta* __restrict__ meta,
                                             float* __restrict__ out,
                                             const float* __restrict__ regs,
                                             const float* __restrict__ anchors,
                                             const float* __restrict__ ccs,
                                             const int* __restrict__ preds,
                                             const unsigned long long* __restrict__ ties) {
  const size_t S = (size_t)BB * CAND_CAP;
  int img = blockIdx.x;
  int tid = threadIdx.x;
  int lane = tid & 63;
  int wid = tid >> 6;

  __shared__ float4 boxo[CAND_CAP];           // offset boxes               16 KB
  __shared__ float4 pay0[CAND_CAP];           // x1,y1,x2,y2                16 KB
  __shared__ float4 pay1[CAND_CAP];           // obj,cc,cp,score            16 KB
  __shared__ unsigned idxA[CAND_CAP];         // anchor idx                  4 KB
  __shared__ unsigned wins[MAXDET];           // winner slots               400 B
  __shared__ float4 lout4[MAXDET * 7 / 4];    // output staging            2.8 KB
  __shared__ unsigned long long slots[2][4];  // spin mailboxes (parity-dbuf)
  float* lout = reinterpret_cast<float*>(lout4);

  unsigned cnt = meta[img].cnt;
  unsigned c_gt = meta[img].c_gt;
  unsigned tcnt = meta[img].tie_cnt;
  if (tcnt > TIE_CAP) tcnt = TIE_CAP;
  unsigned need = (unsigned)TOPK - c_gt;
  if (need > tcnt) need = tcnt;
  int n = (int)(cnt + need);

  float x1o[4], y1o[4], x2o[4], y2o[4], area[4];
  unsigned kh[4], kl[4];

  // ---- (1) main load: 4 slots/lane, boxes to registers AND LDS ----
#pragma unroll
  for (int j = 0; j < 4; ++j) {
    int c = j * 256 + tid;
    size_t o = (size_t)img * CAND_CAP + (size_t)c;
    bool v = c < (int)cnt;
    float vx1 = cand[0 * S + o], vy1 = cand[1 * S + o];
    float vx2 = cand[2 * S + o], vy2 = cand[3 * S + o];
    float vobj = cand[4 * S + o], vcc = cand[5 * S + o];
    float vcp = cand[6 * S + o], vsc = cand[7 * S + o];
    unsigned vai = reinterpret_cast<const unsigned*>(cand + 8 * S)[o];
    if (!v) { vx1 = vy1 = vx2 = vy2 = 0.f; vobj = vcc = vcp = 0.f; vsc = NEGV; vai = 0x7FFFu; }
    float offv = vcp * 4096.0f;
    float a1 = vx1 + offv, b1 = vy1 + offv, a2 = vx2 + offv, b2 = vy2 + offv;
    x1o[j] = a1; y1o[j] = b1; x2o[j] = a2; y2o[j] = b2;
    area[j] = (a2 - a1) * (b2 - b1);
    boxo[c] = make_float4(a1, b1, a2, b2);
    pay0[c] = make_float4(vx1, vy1, vx2, vy2);
    pay1[c] = make_float4(vobj, vcc, vcp, vsc);
    idxA[c] = vai;
    kh[j] = flipKey(vsc);
    kl[j] = (((0x7FFFu - vai) & 0x7FFFu) << 10) | (unsigned)c;
  }
  if (tid < 8) slots[tid >> 2][tid & 3] = 0ull;
  if (tid < MAXDET) wins[tid] = 0xFFFFFFFFu;
  __syncthreads();

  // ---- (2) tie rank-select (wave 0): rank = #ties with bigger 62-bit key ----
  if (wid == 0) {
    const unsigned long long* tptr = ties + (size_t)img * TIE_CAP;
    for (unsigned base = 0; base < tcnt; base += 64) {
      unsigned p = base + (unsigned)lane;
      unsigned long long myk = (p < tcnt) ? tptr[p] : 0ull;
      unsigned rank = 0;
      for (unsigned q2 = 0; q2 < tcnt; ++q2) {
        unsigned long long other = tptr[q2];  // wave-uniform -> broadcast, L2-resident
        rank += (other > myk) ? 1u : 0u;
      }
      if (p < tcnt && rank < need) {
        unsigned idx = 0x7FFFu - (unsigned)(myk & 0x7FFFull);
        unsigned key32 = (unsigned)(myk >> 15);
        size_t g = (size_t)img * NN + idx;
        const float* r = regs + g * 5;
        float d0 = r[0], d1 = r[1], d2 = r[2], d3 = r[3], obj = r[4];
        const float* a = anchors + (size_t)idx * 4;
        float ax1 = a[0], ay1 = a[1], ax2 = a[2], ay2 = a[3];
        float aw = ax2 - ax1, ah = ay2 - ay1;
        float acx = (ax1 + ax2) * 0.5f, acy = (ay1 + ay2) * 0.5f;
        float cx = acx + d0 * aw, cy = acy + d1 * ah;
        float w = aw * expf(d2), h = ah * expf(d3);
        float hw = 0.5f * w, hh = 0.5f * h;
        float x1 = fminf(fmaxf(cx - hw, 0.0f), IMGSZ);
        float y1 = fminf(fmaxf(cy - hh, 0.0f), IMGSZ);
        float x2 = fminf(fmaxf(cx + hw, 0.0f), IMGSZ);
        float y2 = fminf(fmaxf(cy + hh, 0.0f), IMGSZ);
        float cc = ccs[g];
        float cp = (float)preds[g];
        float offv = cp * 4096.0f;
        int c = (int)(cnt + rank);
        boxo[c] = make_float4(x1 + offv, y1 + offv, x2 + offv, y2 + offv);
        pay0[c] = make_float4(x1, y1, x2, y2);
        pay1[c] = make_float4(obj, cc, cp, unflipKey(key32));
        idxA[c] = idx;
      }
    }
  }
  __syncthreads();

  // ---- (3) tie reg-init: owning lanes pull tie slots from LDS ----
#pragma unroll
  for (int j = 0; j < 4; ++j) {
    int c = j * 256 + tid;
    if (c >= (int)cnt && c < n) {
      float4 B = boxo[c];
      float4 p1 = pay1[c];
      unsigned vai = idxA[c];
      x1o[j] = B.x; y1o[j] = B.y; x2o[j] = B.z; y2o[j] = B.w;
      area[j] = (B.z - B.x) * (B.w - B.y);
      kh[j] = flipKey(p1.w);
      kl[j] = (((0x7FFFu - vai) & 0x7FFFu) << 10) | (unsigned)c;
    }
  }
  __syncthreads();  // slots/wins init + LDS stable before loop

  const unsigned validThr = flipKey(NEGV * 0.5f);
  volatile unsigned long long (*vslots)[4] =
      (volatile unsigned long long (*)[4])slots;

  // ---- (4) iteration loop: spin-sync with parallel poll ----
  for (int it = 0; it < MAXDET; ++it) {
    // local max over 4 (64-bit order)
    unsigned mh = kh[0], ml = kl[0];
#pragma unroll
    for (int j = 1; j < 4; ++j) {
      bool g = (kh[j] > mh) || ((kh[j] == mh) && (kl[j] > ml));
      mh = g ? kh[j] : mh;
      ml = g ? kl[j] : ml;
    }
    U64MAX_DPP(mh, ml, 0x111);
    U64MAX_DPP(mh, ml, 0x112);
    U64MAX_DPP(mh, ml, 0x114);
    U64MAX_DPP(mh, ml, 0x118);
    U64MAX_DPP(mh, ml, 0x142);
    U64MAX_DPP(mh, ml, 0x143);
    unsigned Ttag = (unsigned)(it + 1);
    int par = it & 1;
    if (lane == 63) {
      unsigned long long my = ((unsigned long long)Ttag << 57) |
                              ((unsigned long long)mh << 25) |
                              (unsigned long long)(ml & 0x1FFFFFFu);
      vslots[par][wid] = my;
    }
    // parallel poll: lane j watches slot j&3; one ballot tests all four tags
    unsigned long long v;
    do {
      v = vslots[par][lane & 3];
    } while (__ballot((unsigned)(v >> 57) == Ttag) != ~0ull);
    // quad combine: after xor1+xor2 every lane holds max over all 4 slots
    unsigned ch = (unsigned)(v >> 32), cl = (unsigned)v;
    U64MAX_DPP(ch, cl, 0xB1);  // quad_perm xor 1
    U64MAX_DPP(ch, cl, 0x4E);  // quad_perm xor 2
    unsigned bh = (ch << 7) | (cl >> 25);  // winner's kh
    if (bh <= validThr) break;  // uniform; wins[] stays sentinel -> epilogue zero-fills

    int slot = (int)(cl & 1023u);
    if (tid == ((it & 3) << 6)) wins[it] = (unsigned)slot;  // fire-and-forget
    float4 B = boxo[slot];                                  // ONE uniform ds_read_b128
    float areaB = (B.z - B.x) * (B.w - B.y);
#pragma unroll
    for (int j = 0; j < 4; ++j) {
      int c = j * 256 + tid;
      float lx = fmaxf(B.x, x1o[j]), ly = fmaxf(B.y, y1o[j]);
      float rx = fminf(B.z, x2o[j]), ry = fminf(B.w, y2o[j]);
      float iw = fmaxf(rx - lx, 0.f), ih = fmaxf(ry - ly, 0.f);
      float inter = iw * ih;
      float uu = areaB + area[j] - inter;
      float ss = fmaf(2.0f, inter, -uu);  // exact 2i-u in the decision region (Sterbenz)
      float tt = uu * 0x1p-24f;           // exact scale; RN(i/u)>0.5 <=> ss>tt
      bool sup = (uu > 0.f && ss > tt) || (c == slot);
      if (sup) { kh[j] = 0u; kl[j] = 0u; }
    }
  }
  __syncthreads();

  // ---- epilogue: gather winner payloads via wins[], stage rows, flush ----
  if (tid < MAXDET) {
    unsigned w = wins[tid];
    float* row = lout + tid * 7;
    if (w == 0xFFFFFFFFu) {
      row[0] = 0.f; row[1] = 0.f; row[2] = 0.f; row[3] = 0.f;
      row[4] = 0.f; row[5] = 0.f; row[6] = 0.f;
    } else {
      float4 p0 = pay0[w];
      float4 p1 = pay1[w];
      row[0] = p0.x; row[1] = p0.y; row[2] = p0.z; row[3] = p0.w;
      row[4] = p1.x; row[5] = p1.y; row[6] = p1.z;
    }
  }
  __syncthreads();
  float4* go4 = reinterpret_cast<float4*>(out + (size_t)img * MAXDET * 7);
  if (tid < MAXDET * 7 / 4) go4[tid] = lout4[tid];
}

// ---------------- launch ----------------
extern "C" void kernel_launch(void* const* d_in, const int* in_sizes, int n_in,
                              void* d_out, int out_size, void* d_ws, size_t ws_size,
                              hipStream_t stream) {
  const float* regs = (const float*)d_in[0];
  const float* clses = (const float*)d_in[1];
  const float* anchors = (const float*)d_in[2];
  float* out = (float*)d_out;
  char* ws = (char*)d_ws;

  constexpr size_t HIST_BYTES = (size_t)BB * 65536 * 4;  // 4 MiB
  constexpr size_t META_OFF = HIST_BYTES;
  constexpr size_t META_BYTES = 1024;
  constexpr size_t KEYS_OFF = META_OFF + META_BYTES;
  constexpr size_t ARR_BYTES = (size_t)BB * NN * 4;
  constexpr size_t CCS_OFF = KEYS_OFF + ARR_BYTES;
  constexpr size_t PREDS_OFF = CCS_OFF + ARR_BYTES;
  constexpr size_t CAND_OFF = PREDS_OFF + ARR_BYTES;
  constexpr size_t CAND_BYTES = (size_t)10 * BB * CAND_CAP * 4;
  constexpr size_t TIES_OFF = CAND_OFF + CAND_BYTES;

  unsigned* hist1 = (unsigned*)(ws);
  Meta* meta = (Meta*)(ws + META_OFF);
  unsigned* keys = (unsigned*)(ws + KEYS_OFF);
  float* ccs = (float*)(ws + CCS_OFF);
  int* preds = (int*)(ws + PREDS_OFF);
  float* cand = (float*)(ws + CAND_OFF);
  unsigned long long* ties = (unsigned long long*)(ws + TIES_OFF);

  // zero hist1 + meta every launch (ws is not re-poisoned between replays)
  hipMemsetAsync(d_ws, 0, KEYS_OFF, stream);

  k_score<<<BB * BPI_S, 256, 0, stream>>>(regs, clses, keys, ccs, preds, hist1);
  k_scan<<<BB, 256, 0, stream>>>(hist1, meta);
  k_compact<<<BB * BPI_C, 256, 0, stream>>>(regs, anchors, keys, ccs, preds, meta, cand, ties);
  k_nms<<<BB, 256, 0, stream>>>(cand, meta, out, regs, anchors, ccs, preds, ties);
}